// Round 1
// baseline (143.096 us; speedup 1.0000x reference)
//
#include <hip/hip_runtime.h>
#include <math.h>

#define CAPV 0.99f

// ---------------------------------------------------------------------------
// Kernel 1: per-batch angle/diag precompute.
//   cs[b*1024 + p]   = {cos(angles[p] + tanh(mod[b]·w_angle[p])),
//                       sin(...)}
//   diag[b*256 + c]  = clip(clip(tanh(diagonal[c])) + tanh(mod[b]·w_diag[c]))
// 32768 threads total; trivial cost.
// ---------------------------------------------------------------------------
__global__ void pr_precompute(const float* __restrict__ mod,
                              const float* __restrict__ angles,
                              const float* __restrict__ diagonal,
                              const float* __restrict__ w_angle,
                              const float* __restrict__ w_diag,
                              float2* __restrict__ cs,
                              float* __restrict__ diag_out) {
    const int gid = blockIdx.x * blockDim.x + threadIdx.x;   // 0..32767
    const int b = gid >> 10;
    const int p = gid & 1023;

    const float4* m  = (const float4*)(mod + (size_t)b * 256);
    const float4* wr = (const float4*)(w_angle + (size_t)p * 256);
    float acc = 0.f;
#pragma unroll
    for (int k = 0; k < 64; ++k) {
        float4 a = m[k], c = wr[k];
        acc += a.x * c.x + a.y * c.y + a.z * c.z + a.w * c.w;
    }
    const float ang = angles[p] + tanhf(acc);
    float sv, cv;
    sincosf(ang, &sv, &cv);
    cs[gid] = make_float2(cv, sv);

    if (gid < 32 * 256) {
        const int b2 = gid >> 8;
        const int cd = gid & 255;
        const float4* m2 = (const float4*)(mod + (size_t)b2 * 256);
        const float4* w2 = (const float4*)(w_diag + (size_t)cd * 256);
        float a2 = 0.f;
#pragma unroll
        for (int k = 0; k < 64; ++k) {
            float4 u = m2[k], v = w2[k];
            a2 += u.x * v.x + u.y * v.y + u.z * v.z + u.w * v.w;
        }
        float bd = tanhf(diagonal[cd]);
        bd = fminf(fmaxf(bd, -CAPV), CAPV);
        float d = bd + tanhf(a2);
        d = fminf(fmaxf(d, -CAPV), CAPV);
        diag_out[gid] = d;
    }
}

// ---------------------------------------------------------------------------
// Kernel 2: the butterfly.
// Block = 256 threads (4 waves). Block handles one b and 2 rows (128 points).
// Lane layout: chunk = lane>>5 (channels [chunk*128, chunk*128+128)),
//              point = wave*32 + (lane&31).
// Stages 1..7: pair partner = c ^ half, half<=64 -> inside the 128-chunk,
//              pure register math, indices compile-time (full unroll).
// Stage 8:     partner = c ^ 128 -> other chunk = lane ^ 32 -> __shfl_xor.
// Pair index p for a chunk-local left channel i at stage st reduces to
//   p = chunk*64 + jj  (jj = 0..63 compile-time), so LDS reads are
//   ds_read_b64 [lane_base + chunk*512] offset:(soff+jj)*8.
// ---------------------------------------------------------------------------
__global__ __launch_bounds__(256, 2)
void pr_butterfly(const float* __restrict__ x,
                  const float2* __restrict__ cs,
                  const float* __restrict__ diag,
                  float* __restrict__ out) {
    __shared__ __align__(16) float2 cs_lds[1024];
    __shared__ __align__(16) float  diag_lds[256];

    const int tid = threadIdx.x;
    const int blk = blockIdx.x;          // 1024 blocks
    const int b  = blk >> 5;             // 0..31
    const int hp = blk & 31;             // row pair 0..31

    // Stage the per-batch tables into LDS (8 KB + 1 KB).
    {
        const float4* src = (const float4*)(cs + (size_t)b * 1024);  // 512 f4
        float4* dst = (float4*)cs_lds;
        dst[tid]       = src[tid];
        dst[tid + 256] = src[tid + 256];
        if (tid < 64)
            ((float4*)diag_lds)[tid] = ((const float4*)(diag + (size_t)b * 256))[tid];
    }
    __syncthreads();

    const int lane  = tid & 63;
    const int wv    = tid >> 6;
    const int chunk = lane >> 5;                 // 0 or 1
    const int pt    = wv * 32 + (lane & 31);     // 0..127
    const int h     = hp * 2 + (pt >> 6);
    const int w     = pt & 63;
    const unsigned spatial = (unsigned)(h * 64 + w);

    const float* __restrict__ xb = x + (size_t)b * 256 * 4096;
    float* __restrict__ ob = out + (size_t)b * 256 * 4096;
    const unsigned voff = (unsigned)(chunk * 128 * 4096) + spatial;

    float y[128];
#pragma unroll
    for (int k = 0; k < 128; ++k)
        y[k] = xb[voff + (unsigned)k * 4096u];

    // Stages 1..7 — register-local rotations.
    const float2* csl = cs_lds + chunk * 64;
#pragma unroll
    for (int st = 1; st <= 7; ++st) {
        const int half = 1 << (st - 1);
        const int soff = (st - 1) * 128;
#pragma unroll
        for (int jj = 0; jj < 64; ++jj) {
            const int il = ((jj >> (st - 1)) << st) | (jj & (half - 1));
            const int ir = il | half;
            const float2 a = csl[soff + jj];     // {cos, sin}
            const float l = y[il];
            const float r = y[ir];
            y[il] = fmaf(a.x, l,  a.y * r);
            y[ir] = fmaf(a.x, r, -(a.y * l));
        }
    }

    // Stage 8 — cross-chunk via shfl_xor(32). Pair index = i (0..127).
#pragma unroll
    for (int i = 0; i < 128; ++i) {
        const float2 a = cs_lds[896 + i];
        const float part = __shfl_xor(y[i], 32, 64);
        const float t = a.y * part;
        y[i] = fmaf(a.x, y[i], chunk ? -t : t);
    }

    // Diagonal scale + store.
#pragma unroll
    for (int k = 0; k < 128; ++k)
        ob[voff + (unsigned)k * 4096u] = y[k] * diag_lds[chunk * 128 + k];
}

// ---------------------------------------------------------------------------
extern "C" void kernel_launch(void* const* d_in, const int* in_sizes, int n_in,
                              void* d_out, int out_size, void* d_ws, size_t ws_size,
                              hipStream_t stream) {
    const float* x        = (const float*)d_in[0];  // (32,256,64,64)
    const float* mod      = (const float*)d_in[1];  // (32,256)
    const float* angles   = (const float*)d_in[2];  // (1024,)
    const float* diagonal = (const float*)d_in[3];  // (256,)
    const float* w_angle  = (const float*)d_in[4];  // (1024,256)
    const float* w_diag   = (const float*)d_in[5];  // (256,256)
    float* out = (float*)d_out;

    float2* cs   = (float2*)d_ws;                             // 32*1024 float2 = 256 KB
    float*  diag = (float*)((char*)d_ws + 32 * 1024 * sizeof(float2)); // 32 KB

    pr_precompute<<<128, 256, 0, stream>>>(mod, angles, diagonal, w_angle, w_diag, cs, diag);
    pr_butterfly<<<1024, 256, 0, stream>>>(x, cs, diag, out);
}